// Round 4
// baseline (291.127 us; speedup 1.0000x reference)
//
#include <hip/hip_runtime.h>
#include <stdint.h>

// DCT2D: y = Dh @ x @ Dw^T per (b,c); B=32,H=W=512,C=3, fp32 in/out.
// bf16 MFMA (16x16x32), two GEMM passes via bf16 intermediate Y[b,k,c,w].
// R4: BK=64 (8 k-iterations instead of 16). R1-R3 proved scheduling is not
// the lever (identical 93 us across drain/pipeline variants); per-iteration
// cost is ~1750 cy regardless -> halve iteration count, double work/iter.
// 8-chunk (128 B) row swizzles: slot = ch ^ ((row>>1)&7). All waits VMW(0)
// after early issue (no counted-vmcnt bug class). T5 setprio around MFMA.

typedef __bf16 bf16_t;
typedef bf16_t bf16x8 __attribute__((ext_vector_type(8)));
typedef float  f32x4  __attribute__((ext_vector_type(4)));

#define SCHED0 __builtin_amdgcn_sched_barrier(0)
#define SBAR   __builtin_amdgcn_s_barrier()
#define LGKM0  asm volatile("s_waitcnt lgkmcnt(0)" ::: "memory")
#define VMW0   asm volatile("s_waitcnt vmcnt(0)" ::: "memory")

__device__ __forceinline__ uint32_t f2bf(float f) {
    union { float f; uint32_t u; } v; v.f = f;
    uint32_t r = v.u + 0x7fffu + ((v.u >> 16) & 1u);   // RNE
    return r >> 16;
}

__device__ __forceinline__ f32x4 mfma16(bf16x8 a, bf16x8 b, f32x4 c) {
    return __builtin_amdgcn_mfma_f32_16x16x32_bf16(a, b, c, 0, 0, 0);
}

__device__ __forceinline__ void load_lds16(const void* g, void* l) {
    __builtin_amdgcn_global_load_lds(
        (const __attribute__((address_space(1))) uint32_t*)g,
        (__attribute__((address_space(3))) uint32_t*)l, 16, 0, 0);
}

// ---------------- D matrix generation (bf16, row-major D[k][h]) -------------
__global__ __launch_bounds__(256) void gen_dct(uint16_t* __restrict__ Dbf) {
    int idx = blockIdx.x * 256 + threadIdx.x;      // 512*512 elems
    int k = idx >> 9, h = idx & 511;
    int phase = ((2 * h + 1) * k) & 2047;          // exact mod-2048 reduction
    float ang = (float)phase * 3.0679615757712823e-3f;   // pi/1024
    float s = (k == 0) ? 0.04419417382415922f : 0.0625f; // sqrt(1/512), sqrt(2/512)
    Dbf[idx] = (uint16_t)f2bf(__cosf(ang) * s);
}

// ---------------- Pass 1: Y[b,k,c,w] = sum_h D[k,h] * x[b,h,w,c] ------------
// GEMM per b: C[m=k(128-tile), n=remapped (c,w) col (96-tile)], K=h, BK=64.
// A = D tile (128 x 64h bf16, 8 chunks/row) via global_load_lds, source chunk
//     pre-swizzled g = i ^ ((m>>1)&7); read slot = ch ^ ((row>>1)&7).
// B = x tile fp32->bf16 transposed to [col][h] (64 h = 8 chunks), slot XOR
//     swz(col) = ((c>>1)^(c>>3)^(c>>5))&7.
// Per iter: issue A(k+1)+X(k+1) early, compute(k) 24 MFMA/wave, pack B(k+1),
// drain, barrier. 8 iterations.
__global__ __launch_bounds__(256, 2) void pass1(const float* __restrict__ x,
                                                const uint16_t* __restrict__ Dbf,
                                                uint16_t* __restrict__ Y) {
    __shared__ __align__(16) uint16_t Alds[2][128 * 64];   // 32 KB
    __shared__ __align__(16) uint16_t Blds[2][96 * 64];    // 24 KB
    const int t = threadIdx.x;
    const int lane = t & 63, wv = t >> 6;
    const int nt = blockIdx.x;   // j-tile 0..15 (96 cols = 32 w * 3 c)
    const int mt = blockIdx.y;   // k-tile 0..3
    const int b  = blockIdx.z;
    const float* xb = x + (size_t)b * (512 * 1536);

    // A staging: 1024 chunks, 4 per thread. slot q -> row m=q>>3, holds
    // global chunk (q&7) ^ ((m>>1)&7).
    const int qA0 = t, qA1 = t + 256, qA2 = t + 512, qA3 = t + 768;
    const int mA0 = qA0 >> 3, gA0 = (qA0 & 7) ^ ((mA0 >> 1) & 7);
    const int mA1 = qA1 >> 3, gA1 = (qA1 & 7) ^ ((mA1 >> 1) & 7);
    const int mA2 = qA2 >> 3, gA2 = (qA2 & 7) ^ ((mA2 >> 1) & 7);
    const int mA3 = qA3 >> 3, gA3 = (qA3 & 7) ^ ((mA3 >> 1) & 7);
    const uint16_t* As0 = Dbf + (size_t)(mt * 128 + mA0) * 512 + gA0 * 8;
    const uint16_t* As1 = Dbf + (size_t)(mt * 128 + mA1) * 512 + gA1 * 8;
    const uint16_t* As2 = Dbf + (size_t)(mt * 128 + mA2) * 512 + gA2 * 8;
    const uint16_t* As3 = Dbf + (size_t)(mt * 128 + mA3) * 512 + gA3 * 8;

    // B-staging mapping (threads 0..191): jl -> (w,c); col remap so that
    // MFMA col-tiles 2c/2c+1 hold even/odd w (paired bf16 stores).
    const int jl = t % 96;
    const int hh = t / 96;                       // 0/1 -> h-halves of 32
    const int wl = jl / 3, cc = jl - 3 * wl;
    const int ncol = cc * 32 + ((wl >> 1) + ((wl & 1) << 4));
    const int xv = ((ncol >> 1) ^ (ncol >> 3) ^ (ncol >> 5)) & 7;  // chunk XOR
    const int jg = nt * 96 + jl;
    const float* xsrc = xb + (size_t)(hh * 32) * 1536 + jg;

    f32x4 acc[2][6] = {};
    float vx[32];                 // X register bank (fully unrolled -> VGPRs)

    auto issueA = [&](int kk) {
        uint16_t* A = Alds[kk & 1];
        load_lds16(As0 + kk * 64, A + qA0 * 8);
        load_lds16(As1 + kk * 64, A + qA1 * 8);
        load_lds16(As2 + kk * 64, A + qA2 * 8);
        load_lds16(As3 + kk * 64, A + qA3 * 8);
    };
    auto issueX = [&](int kk) {
        if (t < 192) {
            const float* s = xsrc + (size_t)kk * 64 * 1536;
#pragma unroll
            for (int r = 0; r < 32; ++r) vx[r] = s[(size_t)r * 1536];
        }
    };
    auto packB = [&](int kk) {
        if (t < 192) {
            uint32_t p[16];
#pragma unroll
            for (int i = 0; i < 16; ++i)
                p[i] = f2bf(vx[2 * i]) | (f2bf(vx[2 * i + 1]) << 16);
            uint16_t* B = Blds[kk & 1];
#pragma unroll
            for (int u = 0; u < 4; ++u) {
                int slot = (hh * 4 + u) ^ xv;
                *(uint4*)&B[ncol * 64 + slot * 8] =
                    make_uint4(p[4 * u], p[4 * u + 1], p[4 * u + 2], p[4 * u + 3]);
            }
        }
    };
    auto compute = [&](int kk) {
        const uint16_t* A  = Alds[kk & 1];
        const uint16_t* Bl = Blds[kk & 1];
        bf16x8 aq[2][2];
#pragma unroll
        for (int i = 0; i < 2; ++i) {
            int row = (wv * 2 + i) * 16 + (lane & 15);
#pragma unroll
            for (int ks = 0; ks < 2; ++ks) {
                int slot = (ks * 4 + (lane >> 4)) ^ ((row >> 1) & 7);
                aq[i][ks] = *(const bf16x8*)&A[row * 64 + slot * 8];
            }
        }
        __builtin_amdgcn_s_setprio(1);
#pragma unroll
        for (int tt = 0; tt < 6; ++tt) {
            int col = tt * 16 + (lane & 15);
            int xr = ((col >> 1) ^ (col >> 3) ^ (col >> 5)) & 7;
#pragma unroll
            for (int ks = 0; ks < 2; ++ks) {
                int slot = (ks * 4 + (lane >> 4)) ^ xr;
                bf16x8 bq = *(const bf16x8*)&Bl[col * 64 + slot * 8];
                acc[0][tt] = mfma16(aq[0][ks], bq, acc[0][tt]);
                acc[1][tt] = mfma16(aq[1][ks], bq, acc[1][tt]);
            }
        }
        __builtin_amdgcn_s_setprio(0);
    };

    // ---- prologue: stage k=0 ----
    issueA(0); SCHED0;
    issueX(0); SCHED0;
    packB(0);
    LGKM0; VMW0; SBAR; SCHED0;

    for (int kt = 0; kt < 8; ++kt) {
        if (kt < 7) { issueA(kt + 1); SCHED0; issueX(kt + 1); SCHED0; }
        compute(kt);
        if (kt < 7) {
            packB(kt + 1);
            LGKM0; VMW0; SBAR; SCHED0;
        }
    }

    // Epilogue: direct coalesced dword stores (bf16 pair at adjacent w).
    const int wg = nt * 32 + 2 * (lane & 15);
#pragma unroll
    for (int i = 0; i < 2; ++i) {
        int kg = mt * 128 + (wv * 2 + i) * 16 + ((lane >> 4) << 2);
#pragma unroll
        for (int c = 0; c < 3; ++c)
#pragma unroll
            for (int r = 0; r < 4; ++r) {
                uint32_t pk = f2bf(acc[i][2 * c][r]) | (f2bf(acc[i][2 * c + 1][r]) << 16);
                *(uint32_t*)&Y[(size_t)b * 786432 + (size_t)(kg + r) * 1536 + c * 512 + wg] = pk;
            }
    }
}

// ---------------- Pass 2: out[b,k,l,c] = sum_w D[l,w] * Y[b,k,c,w] ----------
// GEMM per b: C[m=kc(96-tile), n=l(128-tile)], K=w, BK=64.
// Both operands via global_load_lds with pre-swizzled sources; uniform
// 7 ops/thread per stage (A: 3, B: 4). Dbuf, issue-early + VMW0 at barrier.
__global__ __launch_bounds__(256, 2) void pass2(const uint16_t* __restrict__ Y,
                                                const uint16_t* __restrict__ Dbf,
                                                float* __restrict__ out) {
    __shared__ __align__(16) char smem[57344];   // 2 x (A 12288 + B 16384)
    const int t = threadIdx.x;
    const int lane = t & 63, wv = t >> 6;
    const int lt = blockIdx.x;   // l-tile 0..3
    const int mt = blockIdx.y;   // kc-tile 0..15
    const int b  = blockIdx.z;
    const size_t yb = (size_t)b * 786432;

    // A: 96 rows x 8 chunks = 768 slots (3/thread); B: 128 x 8 = 1024 (4/thread)
    const int qA0 = t, qA1 = t + 256, qA2 = t + 512;
    const int mA0 = qA0 >> 3, gA0 = (qA0 & 7) ^ ((mA0 >> 1) & 7);
    const int mA1 = qA1 >> 3, gA1 = (qA1 & 7) ^ ((mA1 >> 1) & 7);
    const int mA2 = qA2 >> 3, gA2 = (qA2 & 7) ^ ((mA2 >> 1) & 7);
    const int qB3 = t + 768;
    const int mB3 = qB3 >> 3, gB3 = (qB3 & 7) ^ ((mB3 >> 1) & 7);

    const uint16_t* Ys0 = Y + yb + (size_t)(mt * 96 + mA0) * 512 + gA0 * 8;
    const uint16_t* Ys1 = Y + yb + (size_t)(mt * 96 + mA1) * 512 + gA1 * 8;
    const uint16_t* Ys2 = Y + yb + (size_t)(mt * 96 + mA2) * 512 + gA2 * 8;
    const uint16_t* Ds0 = Dbf + (size_t)(lt * 128 + mA0) * 512 + gA0 * 8;
    const uint16_t* Ds1 = Dbf + (size_t)(lt * 128 + mA1) * 512 + gA1 * 8;
    const uint16_t* Ds2 = Dbf + (size_t)(lt * 128 + mA2) * 512 + gA2 * 8;
    const uint16_t* Ds3 = Dbf + (size_t)(lt * 128 + mB3) * 512 + gB3 * 8;

    f32x4 acc[6][2] = {};

    auto stage = [&](int kt) {
        const int buf = kt & 1;
        uint16_t* Al = (uint16_t*)(smem + buf * 28672);
        uint16_t* Bl = (uint16_t*)(smem + buf * 28672 + 12288);
        load_lds16(Ys0 + kt * 64, Al + qA0 * 8);
        load_lds16(Ys1 + kt * 64, Al + qA1 * 8);
        load_lds16(Ys2 + kt * 64, Al + qA2 * 8);
        load_lds16(Ds0 + kt * 64, Bl + qA0 * 8);
        load_lds16(Ds1 + kt * 64, Bl + qA1 * 8);
        load_lds16(Ds2 + kt * 64, Bl + qA2 * 8);
        load_lds16(Ds3 + kt * 64, Bl + qB3 * 8);
    };
    auto compute = [&](int kt) {
        const int buf = kt & 1;
        const uint16_t* Al = (const uint16_t*)(smem + buf * 28672);
        const uint16_t* Bl = (const uint16_t*)(smem + buf * 28672 + 12288);
        bf16x8 bq[2][2];
#pragma unroll
        for (int p = 0; p < 2; ++p) {
            int row = (wv * 2 + p) * 16 + (lane & 15);
#pragma unroll
            for (int ks = 0; ks < 2; ++ks) {
                int slot = (ks * 4 + (lane >> 4)) ^ ((row >> 1) & 7);
                bq[p][ks] = *(const bf16x8*)&Bl[row * 64 + slot * 8];
            }
        }
        __builtin_amdgcn_s_setprio(1);
#pragma unroll
        for (int tt = 0; tt < 6; ++tt) {
            int row = tt * 16 + (lane & 15);
#pragma unroll
            for (int ks = 0; ks < 2; ++ks) {
                int slot = (ks * 4 + (lane >> 4)) ^ ((row >> 1) & 7);
                bf16x8 aq = *(const bf16x8*)&Al[row * 64 + slot * 8];
                acc[tt][0] = mfma16(aq, bq[0][ks], acc[tt][0]);
                acc[tt][1] = mfma16(aq, bq[1][ks], acc[tt][1]);
            }
        }
        __builtin_amdgcn_s_setprio(0);
    };

    // prologue
    stage(0); SCHED0;
    VMW0; SBAR; SCHED0;

    for (int kt = 0; kt < 8; ++kt) {
        if (kt < 7) { stage(kt + 1); SCHED0; }
        compute(kt);
        if (kt < 7) { VMW0; SBAR; SCHED0; }
    }

    // Epilogue: transpose [kc][l] -> out rows [k][(l,c)] in two l-halves
    // via padded LDS (96 x 65 fp32 = 24.96 KB, aliases the smem union).
    __syncthreads();
    float* El = (float*)smem;
    const int kloc = t >> 3, sub = t & 7;   // 32 k-rows, 8 threads per row
#pragma unroll
    for (int hf = 0; hf < 2; ++hf) {
        __syncthreads();
        if ((wv >> 1) == hf) {              // waves owning l in [hf*64, hf*64+64)
#pragma unroll
            for (int tt = 0; tt < 6; ++tt)
#pragma unroll
                for (int p = 0; p < 2; ++p) {
                    int m = tt * 16 + ((lane >> 4) << 2);
                    int lc = ((wv & 1) * 2 + p) * 16 + (lane & 15);  // local l
#pragma unroll
                    for (int r = 0; r < 4; ++r)
                        El[(m + r) * 65 + lc] = acc[tt][p][r];
                }
        }
        __syncthreads();
        size_t ob = (size_t)b * 786432 + (size_t)(mt * 32 + kloc) * 1536 +
                    lt * 384 + hf * 192 + sub * 24;
#pragma unroll
        for (int q = 0; q < 6; ++q) {
            int o0 = hf * 192 + sub * 24 + q * 4;
            float4 v;
            v.x = El[(kloc * 3 + ((o0 + 0) % 3)) * 65 + ((o0 + 0) / 3 - hf * 64)];
            v.y = El[(kloc * 3 + ((o0 + 1) % 3)) * 65 + ((o0 + 1) / 3 - hf * 64)];
            v.z = El[(kloc * 3 + ((o0 + 2) % 3)) * 65 + ((o0 + 2) / 3 - hf * 64)];
            v.w = El[(kloc * 3 + ((o0 + 3) % 3)) * 65 + ((o0 + 3) / 3 - hf * 64)];
            *(float4*)&out[ob + q * 4] = v;
        }
    }
}

// ---------------------------------------------------------------------------
extern "C" void kernel_launch(void* const* d_in, const int* in_sizes, int n_in,
                              void* d_out, int out_size, void* d_ws, size_t ws_size,
                              hipStream_t stream) {
    (void)in_sizes; (void)n_in; (void)out_size; (void)ws_size;
    const float* x = (const float*)d_in[0];
    float* out = (float*)d_out;
    uint16_t* Dbf = (uint16_t*)d_ws;                 // 512*512 bf16 = 512 KB
    uint16_t* Y   = (uint16_t*)d_ws + 512 * 512;     // 32*512*512*3 bf16 = 48 MB

    gen_dct<<<1024, 256, 0, stream>>>(Dbf);
    dim3 g1(16, 4, 32);
    pass1<<<g1, 256, 0, stream>>>(x, Dbf, Y);
    dim3 g2(4, 16, 32);
    pass2<<<g2, 256, 0, stream>>>(Y, Dbf, out);
}